// Round 5
// baseline (527.275 us; speedup 1.0000x reference)
//
#include <hip/hip_runtime.h>
#include <math.h>

#ifndef M_PI
#define M_PI 3.14159265358979323846
#endif

// B=64, C=3, H=W=512.
// Loss = mean_b | mean_hf(log10 PSD(gen_b)) - mean_hf(log10 PSD(tgt_b)) |
// hf region (unshifted freq): element EXCLUDED iff ky and kx both in [0,64)u[448,512).
// With ky = cc + 8dd + 64e (cc,dd in [0,8)): ky<64 <=> e==0, ky>=448 <=> e==7.
// count = 512^2 - 128^2 = 245760.
//
// FFT: 512 = 8*8*8 Cooley-Tukey, per-wave, 8 complex regs/lane, two wave-private
// LDS transposes with compile-time-only ordering (R6, verified absmax 0.0: the
// per-wave DS pipe is in-order; no s_waitcnt needed for same-wave RAW).
// R7 (verified): col pass = one wave per conjugate column pair, zero barriers,
// no atomics (per-wave double2 partials + tiny reduce kernel).
//
// R8 (unverified last round - acquisition timeout; resubmitted verbatim):
//   row pass restructured for HBM store efficiency.
//   Counters showed row_fft = 167us at VALU 14% / HBM 25% / LDS-floor: the 64B
//   column-segment scatter stores (8-row blocks) are the limiter.
//   Now: 16 rows per block (8 waves x 2 sequential FFTs; row-B loads prefetch
//   under FFT-A), 64KB LDS staging (region j = row r0+j, slot (col+65j)&511 --
//   bijective per region, bank-floor on staging writes AND both gather reads),
//   gather emits float4 stores: 8 lanes cover a 128B-contiguous column segment.
//   Store transactions halve; grid 4096 -> 2048 blocks.
//
// ws layout: [0,2048) tw[256] ; [2048,3072) double accum[128] ;
//            [4096, 4096+262144) double2 partial[64*256] ;
//            [266240, ...) scratch (16 KB-aligned at 266240 = 65*4096).
// scratch column index "col" encodes kx: kx(col) = ((col>>3)&7) + 8*(col&7) + 64*(col>>6)
//                                        col(kx) = 64*(kx>>6) + 8*(kx&7) + ((kx>>3)&7)

__device__ __forceinline__ float2 cmulf(float2 a, float2 b) {
    return make_float2(fmaf(a.x, b.x, -(a.y * b.y)), fmaf(a.x, b.y, a.y * b.x));
}
__device__ __forceinline__ float2 caddf(float2 a, float2 b){ return make_float2(a.x+b.x, a.y+b.y); }
__device__ __forceinline__ float2 csubf(float2 a, float2 b){ return make_float2(a.x-b.x, a.y-b.y); }

// Wave-local LDS ordering point: compile-time only (DS pipe is in-order per wave).
__device__ __forceinline__ void lds_order() {
    __builtin_amdgcn_sched_barrier(0);
}

// natural-order 8-point DFT: v[k] <- sum_a v[a] W_8^{ak}
__device__ __forceinline__ void dft8(float2 v[8]) {
    const float S = 0.70710678118654752440f;
    float2 a0=caddf(v[0],v[4]), a1=caddf(v[1],v[5]), a2=caddf(v[2],v[6]), a3=caddf(v[3],v[7]);
    float2 b0=csubf(v[0],v[4]);
    float2 t1=csubf(v[1],v[5]);
    float2 t2=csubf(v[2],v[6]);
    float2 t3=csubf(v[3],v[7]);
    float2 b1=make_float2(S*(t1.x+t1.y), S*(t1.y-t1.x));   // *(S,-S) = W8^1
    float2 b2=make_float2(t2.y, -t2.x);                    // *(-i)   = W8^2
    float2 b3=make_float2(S*(t3.y-t3.x), -S*(t3.x+t3.y));  // *(-S,-S)= W8^3
    float2 c0=caddf(a0,a2), c1=caddf(a1,a3), c2=csubf(a0,a2);
    float2 u3=csubf(a1,a3); float2 c3=make_float2(u3.y,-u3.x);
    float2 d0=caddf(b0,b2), d1=caddf(b1,b3), d2=csubf(b0,b2);
    float2 w3=csubf(b1,b3); float2 d3=make_float2(w3.y,-w3.x);
    v[0]=caddf(c0,c1); v[4]=csubf(c0,c1);
    v[2]=caddf(c2,c3); v[6]=csubf(c2,c3);
    v[1]=caddf(d0,d1); v[5]=csubf(d0,d1);
    v[3]=caddf(d2,d3); v[7]=csubf(d2,d3);
}

// v[c] *= w^c, c=1..7. Power tree: short dependency chain, good ILP.
__device__ __forceinline__ void twapply(float2 v[8], float2 w) {
    const float2 w2 = cmulf(w,  w);
    const float2 w3 = cmulf(w2, w);
    const float2 w4 = cmulf(w2, w2);
    const float2 w5 = cmulf(w2, w3);
    const float2 w6 = cmulf(w3, w3);
    const float2 w7 = cmulf(w4, w3);
    v[1] = cmulf(v[1], w);
    v[2] = cmulf(v[2], w2);
    v[3] = cmulf(v[3], w3);
    v[4] = cmulf(v[4], w4);
    v[5] = cmulf(v[5], w5);
    v[6] = cmulf(v[6], w6);
    v[7] = cmulf(v[7], w7);
}

// Per-wave 512-pt FFT. In: v[a] = x[64a + lane]. Out: lane L, reg e = X[(L>>3) + 8*(L&7) + 64e].
// W = this wave's PRIVATE 512-float2 LDS region. No block-wide sync inside.
__device__ __forceinline__ void fft512_reg(float2 v[8], float2* __restrict__ W,
                                           const float2* __restrict__ twg, int lane) {
    dft8(v);
    twapply(v, twg[lane]);                                   // W_512^m, m = lane
    // T1 write: slot(c,m) = 64c + ((m + 2c)&63)  -> rotation: bijective, bank floor
#pragma unroll
    for (int c = 0; c < 8; ++c) W[(c<<6) + ((lane + 2*c)&63)] = v[c];
    lds_order();
    {   // T1 read: lane (c,p) takes m = 8b+p
        const int c = lane>>3, p = lane&7, base = c<<6, off = p + 2*c;
#pragma unroll
        for (int bb = 0; bb < 8; ++bb) v[bb] = W[base + (((bb<<3) + off)&63)];
    }
    lds_order();
    dft8(v);
    twapply(v, twg[(lane&7)<<3]);                            // W_64^p = W_512^{8p}
    {   // T2 write: slot(c,p,d) at 64c + ((8d + (p^d) + 2c)&63)  (XOR: bijective)
        const int c = lane>>3, p = lane&7, base = c<<6, r2 = 2*c;
#pragma unroll
        for (int d = 0; d < 8; ++d) W[base + (((d<<3) + (p^d) + r2)&63)] = v[d];
    }
    lds_order();
    {   // T2 read: lane (c,d) takes p = 0..7
        const int c = lane>>3, d = lane&7, base = c<<6, off = (d<<3) + 2*c;
#pragma unroll
        for (int p = 0; p < 8; ++p) v[p] = W[base + ((off + (p^d))&63)];
    }
    lds_order();
    dft8(v);
}

__global__ void twiddle_kernel(float2* __restrict__ tw) {
    const int k = threadIdx.x;            // 0..255
    const double ang = -2.0 * M_PI * (double)k / 512.0;
    tw[k] = make_float2((float)cos(ang), (float)sin(ang));
}

// Pass 1 (R8): grayscale + pack (gen=re, tgt=im) + row FFT; transposed scratch write.
// Block = 512 thr = 8 waves; block owns 16 rows (wave w: rows r0+w and r0+8+w).
// Grid = chunk*32.
__global__ __launch_bounds__(512, 4)
void row_fft_kernel(const float* __restrict__ gen, const float* __restrict__ tgt,
                    const float2* __restrict__ twg, float2* __restrict__ scratch,
                    int b0) {
    __shared__ float2 SBUF[16 * 512];     // 64 KB: region j holds row r0+j (slot (col+65j)&511)
    const int tid = threadIdx.x, wave = tid>>6, lane = tid&63;
    const int img = blockIdx.x>>5, rb = blockIdx.x&31;
    const int b = b0 + img, r0 = rb<<4;
    const int rA = r0 + wave, rB = r0 + 8 + wave;

    const size_t baseA = ((size_t)b * 3 * 512 + rA) * 512;
    const size_t baseB = ((size_t)b * 3 * 512 + rB) * 512;
    const float* gRA = gen + baseA; const float* gGA = gRA + 262144; const float* gBA = gGA + 262144;
    const float* tRA = tgt + baseA; const float* tGA = tRA + 262144; const float* tBA = tGA + 262144;
    const float* gRB = gen + baseB; const float* gGB = gRB + 262144; const float* gBB = gGB + 262144;
    const float* tRB = tgt + baseB; const float* tGB = tRB + 262144; const float* tBB = tGB + 262144;

    float2 va[8], vb[8];
#pragma unroll
    for (int a = 0; a < 8; ++a) {          // row A loads (coalesced dword, 64 lanes consecutive)
        const int idx = (a<<6) + lane;
        const float gg = fmaf(0.299f, gRA[idx], fmaf(0.587f, gGA[idx], fmaf(0.114f, gBA[idx], 1.0f))) * 0.5f;
        const float tt = fmaf(0.299f, tRA[idx], fmaf(0.587f, tGA[idx], fmaf(0.114f, tBA[idx], 1.0f))) * 0.5f;
        va[a] = make_float2(gg, tt);
    }
#pragma unroll
    for (int a = 0; a < 8; ++a) {          // row B loads: issued now, consumed after FFT A
        const int idx = (a<<6) + lane;
        const float gg = fmaf(0.299f, gRB[idx], fmaf(0.587f, gGB[idx], fmaf(0.114f, gBB[idx], 1.0f))) * 0.5f;
        const float tt = fmaf(0.299f, tRB[idx], fmaf(0.587f, tGB[idx], fmaf(0.114f, tBB[idx], 1.0f))) * 0.5f;
        vb[a] = make_float2(gg, tt);
    }

    float2* WA = SBUF + (wave<<9);         // region j = wave      (row rA)
    float2* WB = SBUF + ((8+wave)<<9);     // region j = 8+wave    (row rB)

    fft512_reg(va, WA, twg, lane);
    {   // stage A into region j=wave: slot (col + 65j)&511, col = 64e + lane
        const int rot = 65 * wave;
#pragma unroll
        for (int e = 0; e < 8; ++e) WA[(((e<<6) + lane) + rot) & 511] = va[e];
    }
    fft512_reg(vb, WB, twg, lane);
    {   // stage B into region j=8+wave
        const int rot = 65 * (8 + wave);
#pragma unroll
        for (int e = 0; e < 8; ++e) WB[(((e<<6) + lane) + rot) & 511] = vb[e];
    }
    __syncthreads();                       // REAL barrier: gather reads ALL 16 regions

    // gather + store: thread (cg=tid>>3, u=tid&7) handles col=cg+64it, rows r0+2u, r0+2u+1.
    // 8 lanes (fixed cg) cover 16 consecutive r = 128B contiguous; float4 stores.
    const size_t obase = (size_t)img << 18;   // img * 512*512
    const int cg = tid>>3, u = tid&7, j0 = u<<1;
    const int rotl0 = 65*j0, rotl1 = 65*(j0+1);
    float2* s0 = SBUF + (j0<<9);
    float2* s1 = SBUF + ((j0+1)<<9);
#pragma unroll
    for (int it = 0; it < 8; ++it) {
        const int col = cg + (it<<6);
        const float2 x0 = s0[(col + rotl0) & 511];
        const float2 x1 = s1[(col + rotl1) & 511];
        float4 st = make_float4(x0.x, x0.y, x1.x, x1.y);
        *reinterpret_cast<float4*>(&scratch[obase + ((size_t)col<<9) + r0 + j0]) = st;
    }
}

// PSD combine for one element: F1 = Z[ky][kx], F2 = Z[-ky][-kx].
__device__ __forceinline__ void accum_psd(float2 F1, float2 F2, double& sg, double& st) {
    const float ar = 0.5f*(F1.x + F2.x), ai = 0.5f*(F1.y - F2.y);   // gen spectrum
    const float br = 0.5f*(F1.y + F2.y), bi = 0.5f*(F2.x - F1.x);   // tgt spectrum
    const float pg = fmaf(ar, ar, ai*ai) + 1e-10f;
    const float pt = fmaf(br, br, bi*bi) + 1e-10f;
    sg += (double)log10f(pg);
    st += (double)log10f(pt);
}

// Pass 2 (R7): one WAVE per conjugate column pair. Block = 256 thr = 4 waves
// = 4 independent pairs. Grid = chunk*64. NO __syncthreads anywhere.
__global__ __launch_bounds__(256, 4)
void col_fft_reduce_kernel(const float2* __restrict__ scratch,
                           const float2* __restrict__ twg,
                           double2* __restrict__ partial, int b0) {
    __shared__ float2 SBUF[4 * 512];      // 16 KB: one private 512-float2 region per wave
    const int tid = threadIdx.x, wave = tid>>6, lane = tid&63;
    const int gw = (blockIdx.x<<2) + wave;     // global wave id in dispatch
    const int img = gw>>8, t = gw&255;
    const int b = b0 + img;
    const int kxA = t;
    const int kxB = (t == 0) ? 256 : 512 - t;
    const int colA = ((kxA>>6)<<6) + ((kxA&7)<<3) + ((kxA>>3)&7);
    const int colB = ((kxB>>6)<<6) + ((kxB&7)<<3) + ((kxB>>3)&7);
    float2* W = SBUF + (wave<<9);

    const float2* srcA = scratch + ((size_t)img<<18) + ((size_t)colA<<9);
    const float2* srcB = scratch + ((size_t)img<<18) + ((size_t)colB<<9);
    float2 va[8], vb[8];
#pragma unroll
    for (int a = 0; a < 8; ++a) va[a] = srcA[(a<<6) + lane];    // coalesced dwordx2
#pragma unroll
    for (int a = 0; a < 8; ++a) vb[a] = srcB[(a<<6) + lane];    // prefetch under FFT A

    fft512_reg(va, W, twg, lane);

    const int cc = lane>>3, dd = lane&7;
    const int kyb = cc + (dd<<3);            // ky = kyb + 64e

    // publish A natural-ky, read reversed into regs (wave-private, in-order DS)
#pragma unroll
    for (int e = 0; e < 8; ++e) W[kyb + (e<<6)] = va[e];
    lds_order();
    float2 aRev[8];
#pragma unroll
    for (int e = 0; e < 8; ++e) aRev[e] = W[(512 - (kyb + (e<<6))) & 511];
    lds_order();                             // keep FFT B's writes after these reads

    fft512_reg(vb, W, twg, lane);

#pragma unroll
    for (int e = 0; e < 8; ++e) W[kyb + (e<<6)] = vb[e];
    lds_order();
    float2 bRev[8];
#pragma unroll
    for (int e = 0; e < 8; ++e) bRev[e] = W[(512 - (kyb + (e<<6))) & 511];
    lds_order();

    // exclusion: column in box-kx  =>  skip e==0 (ky<64) and e==7 (ky>=448)
    const bool kxinA = (t < 64);             // kxA in [0,64)
    const bool kxinB = (t >= 1 && t <= 64);  // kxB = 512-t in [448,512)

    double sg = 0.0, st = 0.0;
    if (t == 0) {   // both columns self-conjugate: partner is own reversed
#pragma unroll
        for (int e = 0; e < 8; ++e) {
            if (!(kxinA && (e == 0 || e == 7))) accum_psd(va[e], aRev[e], sg, st);
            accum_psd(vb[e], bRev[e], sg, st);   // kx=256 never in box
        }
    } else {        // partner of A is B and vice versa
#pragma unroll
        for (int e = 0; e < 8; ++e) {
            if (!(kxinA && (e == 0 || e == 7))) accum_psd(va[e], bRev[e], sg, st);
            if (!(kxinB && (e == 0 || e == 7))) accum_psd(vb[e], aRev[e], sg, st);
        }
    }
#pragma unroll
    for (int off = 32; off; off >>= 1) {
        sg += __shfl_down(sg, off);
        st += __shfl_down(st, off);
    }
    if (lane == 0) partial[((size_t)b<<8) + t] = make_double2(sg, st);
}

// Sum the 256 per-pair partials of each image into accum[128]. Grid = 64 blocks.
__global__ __launch_bounds__(256)
void reduce_partial_kernel(const double2* __restrict__ partial,
                           double* __restrict__ accum) {
    __shared__ double2 red[4];
    const int img = blockIdx.x, tid = threadIdx.x, wave = tid>>6, lane = tid&63;
    const double2 p = partial[((size_t)img<<8) + tid];
    double sg = p.x, st = p.y;
#pragma unroll
    for (int off = 32; off; off >>= 1) {
        sg += __shfl_down(sg, off);
        st += __shfl_down(st, off);
    }
    if (lane == 0) red[wave] = make_double2(sg, st);
    __syncthreads();
    if (tid == 0) {
        double SG = 0.0, ST = 0.0;
#pragma unroll
        for (int w = 0; w < 4; ++w) { SG += red[w].x; ST += red[w].y; }
        accum[img] = SG;
        accum[64 + img] = ST;
    }
}

__global__ void finalize_kernel(const double* __restrict__ accum,
                                float* __restrict__ out) {
    const int lane = threadIdx.x;   // 64
    double d = fabs(accum[lane] - accum[64 + lane]) * (1.0 / 245760.0);
#pragma unroll
    for (int off = 32; off; off >>= 1) d += __shfl_down(d, off);
    if (lane == 0) out[0] = (float)(d * (1.0 / 64.0));   // WEIGHT = 1.0
}

extern "C" void kernel_launch(void* const* d_in, const int* in_sizes, int n_in,
                              void* d_out, int out_size, void* d_ws, size_t ws_size,
                              hipStream_t stream) {
    (void)in_sizes; (void)n_in; (void)out_size;
    const float* gen = (const float*)d_in[0];
    const float* tgt = (const float*)d_in[1];
    float*   out     = (float*)d_out;
    float2*  tw      = (float2*)d_ws;
    double*  accum   = (double*)((char*)d_ws + 2048);
    double2* partial = (double2*)((char*)d_ws + 4096);            // 64*256*16 B = 256 KB
    float2*  scratch = (float2*)((char*)d_ws + 266240);           // 65*4096

    const size_t per_img = (size_t)512 * 512 * sizeof(float2);
    const size_t avail = (ws_size > 266240) ? (ws_size - 266240) : 0;
    int chunk = 64;                      // 128 MB scratch if it fits (L3-resident)
    while (chunk > 1 && (size_t)chunk * per_img > avail) chunk >>= 1;

    twiddle_kernel<<<1, 256, 0, stream>>>(tw);
    for (int b0 = 0; b0 < 64; b0 += chunk) {
        row_fft_kernel<<<dim3(chunk * 32), dim3(512), 0, stream>>>(gen, tgt, tw, scratch, b0);
        col_fft_reduce_kernel<<<dim3(chunk * 64), dim3(256), 0, stream>>>(scratch, tw, partial, b0);
    }
    reduce_partial_kernel<<<dim3(64), dim3(256), 0, stream>>>(partial, accum);
    finalize_kernel<<<1, 64, 0, stream>>>(accum, out);
}

// Round 7
// 492.712 us; speedup vs baseline: 1.0702x; 1.0702x over previous
//
#include <hip/hip_runtime.h>
#include <math.h>

#ifndef M_PI
#define M_PI 3.14159265358979323846
#endif

// B=64, C=3, H=W=512.
// Loss = mean_b | mean_hf(log10 PSD(gen_b)) - mean_hf(log10 PSD(tgt_b)) |
// hf region (unshifted freq): element EXCLUDED iff ky and kx both in [0,64)u[448,512).
// With ky = cc + 8dd + 64e (cc,dd in [0,8)): ky<64 <=> e==0, ky>=448 <=> e==7.
// count = 512^2 - 128^2 = 245760.
//
// FFT: 512 = 8*8*8 Cooley-Tukey, per-wave, 8 complex regs/lane, two wave-private
// LDS transposes with compile-time-only ordering (R6, verified absmax 0.0).
// R7 (verified): col pass = one wave per conjugate column pair, zero barriers,
// no atomics (per-wave double2 partials + tiny reduce kernel).
// R8 (REGRESSED, reverted): 16-row blocks halved occupancy (40%), VGPR 32->64,
// FETCH +80MiB / WRITE +160MiB amplification. Lesson: keep 8-row/32KB blocks.
//
// R9 (resubmitted verbatim -- acquisition timeout, never ran):
//   writer-contiguous scratch layout.
//   scratch[img][rg][col][j]  (rg = r>>3, j = r&7), flat float2 index
//     img*2^18 + rg*4096 + col*8 + j.
//   Row gather store address = obase + rg*4096 + it*512 + tid -> each block
//   writes ONE contiguous 32KB region (512B per wave-instruction). The 4KB-
//   stride 64B scatter that limited R7's row pass is eliminated.
//   Col kernel reads move to 8x64B segments 32KB apart per instruction --
//   L3-resident scratch (written immediately prior), 64B = native sector.
//   NOTE: effective chunk = 32 given ws_size (shrink loop) -> 2 row + 2 col
//   dispatches per iteration; row is ~2/3 of total time, hence this target.
//
// ws layout: [0,2048) tw[256] ; [2048,3072) double accum[128] ;
//            [4096, 4096+262144) double2 partial[64*256] ;
//            [266240, ...) scratch (16 KB-aligned at 266240 = 65*4096).
// col index encodes kx: col(kx) = 64*(kx>>6) + 8*(kx&7) + ((kx>>3)&7)

__device__ __forceinline__ float2 cmulf(float2 a, float2 b) {
    return make_float2(fmaf(a.x, b.x, -(a.y * b.y)), fmaf(a.x, b.y, a.y * b.x));
}
__device__ __forceinline__ float2 caddf(float2 a, float2 b){ return make_float2(a.x+b.x, a.y+b.y); }
__device__ __forceinline__ float2 csubf(float2 a, float2 b){ return make_float2(a.x-b.x, a.y-b.y); }

// Wave-local LDS ordering point: compile-time only (DS pipe is in-order per wave).
__device__ __forceinline__ void lds_order() {
    __builtin_amdgcn_sched_barrier(0);
}

// natural-order 8-point DFT: v[k] <- sum_a v[a] W_8^{ak}
__device__ __forceinline__ void dft8(float2 v[8]) {
    const float S = 0.70710678118654752440f;
    float2 a0=caddf(v[0],v[4]), a1=caddf(v[1],v[5]), a2=caddf(v[2],v[6]), a3=caddf(v[3],v[7]);
    float2 b0=csubf(v[0],v[4]);
    float2 t1=csubf(v[1],v[5]);
    float2 t2=csubf(v[2],v[6]);
    float2 t3=csubf(v[3],v[7]);
    float2 b1=make_float2(S*(t1.x+t1.y), S*(t1.y-t1.x));   // *(S,-S) = W8^1
    float2 b2=make_float2(t2.y, -t2.x);                    // *(-i)   = W8^2
    float2 b3=make_float2(S*(t3.y-t3.x), -S*(t3.x+t3.y));  // *(-S,-S)= W8^3
    float2 c0=caddf(a0,a2), c1=caddf(a1,a3), c2=csubf(a0,a2);
    float2 u3=csubf(a1,a3); float2 c3=make_float2(u3.y,-u3.x);
    float2 d0=caddf(b0,b2), d1=caddf(b1,b3), d2=csubf(b0,b2);
    float2 w3=csubf(b1,b3); float2 d3=make_float2(w3.y,-w3.x);
    v[0]=caddf(c0,c1); v[4]=csubf(c0,c1);
    v[2]=caddf(c2,c3); v[6]=csubf(c2,c3);
    v[1]=caddf(d0,d1); v[5]=csubf(d0,d1);
    v[3]=caddf(d2,d3); v[7]=csubf(d2,d3);
}

// v[c] *= w^c, c=1..7. Power tree: short dependency chain, good ILP.
__device__ __forceinline__ void twapply(float2 v[8], float2 w) {
    const float2 w2 = cmulf(w,  w);
    const float2 w3 = cmulf(w2, w);
    const float2 w4 = cmulf(w2, w2);
    const float2 w5 = cmulf(w2, w3);
    const float2 w6 = cmulf(w3, w3);
    const float2 w7 = cmulf(w4, w3);
    v[1] = cmulf(v[1], w);
    v[2] = cmulf(v[2], w2);
    v[3] = cmulf(v[3], w3);
    v[4] = cmulf(v[4], w4);
    v[5] = cmulf(v[5], w5);
    v[6] = cmulf(v[6], w6);
    v[7] = cmulf(v[7], w7);
}

// Per-wave 512-pt FFT. In: v[a] = x[64a + lane]. Out: lane L, reg e = X[(L>>3) + 8*(L&7) + 64e].
// W = this wave's PRIVATE 512-float2 LDS region. No block-wide sync inside.
__device__ __forceinline__ void fft512_reg(float2 v[8], float2* __restrict__ W,
                                           const float2* __restrict__ twg, int lane) {
    dft8(v);
    twapply(v, twg[lane]);                                   // W_512^m, m = lane
    // T1 write: slot(c,m) = 64c + ((m + 2c)&63)  -> rotation: bijective, bank floor
#pragma unroll
    for (int c = 0; c < 8; ++c) W[(c<<6) + ((lane + 2*c)&63)] = v[c];
    lds_order();
    {   // T1 read: lane (c,p) takes m = 8b+p
        const int c = lane>>3, p = lane&7, base = c<<6, off = p + 2*c;
#pragma unroll
        for (int bb = 0; bb < 8; ++bb) v[bb] = W[base + (((bb<<3) + off)&63)];
    }
    lds_order();
    dft8(v);
    twapply(v, twg[(lane&7)<<3]);                            // W_64^p = W_512^{8p}
    {   // T2 write: slot(c,p,d) at 64c + ((8d + (p^d) + 2c)&63)  (XOR: bijective)
        const int c = lane>>3, p = lane&7, base = c<<6, r2 = 2*c;
#pragma unroll
        for (int d = 0; d < 8; ++d) W[base + (((d<<3) + (p^d) + r2)&63)] = v[d];
    }
    lds_order();
    {   // T2 read: lane (c,d) takes p = 0..7
        const int c = lane>>3, d = lane&7, base = c<<6, off = (d<<3) + 2*c;
#pragma unroll
        for (int p = 0; p < 8; ++p) v[p] = W[base + ((off + (p^d))&63)];
    }
    lds_order();
    dft8(v);
}

__global__ void twiddle_kernel(float2* __restrict__ tw) {
    const int k = threadIdx.x;            // 0..255
    const double ang = -2.0 * M_PI * (double)k / 512.0;
    tw[k] = make_float2((float)cos(ang), (float)sin(ang));
}

// Pass 1 (R7 structure + R9 layout): grayscale + pack + row FFT; streaming scratch write.
// Block = 512 thr = 8 waves = 8 rows. Grid = chunk*64.
__global__ __launch_bounds__(512, 4)
void row_fft_kernel(const float* __restrict__ gen, const float* __restrict__ tgt,
                    const float2* __restrict__ twg, float2* __restrict__ scratch,
                    int b0) {
    __shared__ float2 SBUF[8 * 512];      // 32 KB: per-wave FFT region, then reused for out-staging
    const int tid = threadIdx.x, wave = tid>>6, lane = tid&63;
    const int img = blockIdx.x>>6, rg = blockIdx.x&63;
    const int b = b0 + img, r = (rg<<3) + wave;

    const size_t rowoff = ((size_t)b * 3 * 512 + r) * 512;
    const float* gR = gen + rowoff; const float* gG = gR + 262144; const float* gB = gG + 262144;
    const float* tR = tgt + rowoff; const float* tG = tR + 262144; const float* tB = tG + 262144;

    float2 v[8];
#pragma unroll
    for (int a = 0; a < 8; ++a) {          // coalesced dword loads, 64 lanes consecutive
        const int idx = (a<<6) + lane;
        const float gg = fmaf(0.299f, gR[idx], fmaf(0.587f, gG[idx], fmaf(0.114f, gB[idx], 1.0f))) * 0.5f;
        const float tt = fmaf(0.299f, tR[idx], fmaf(0.587f, tG[idx], fmaf(0.114f, tB[idx], 1.0f))) * 0.5f;
        v[a] = make_float2(gg, tt);        // (gray01(gen), gray01(tgt))
    }

    float2* W = SBUF + (wave<<9);
    fft512_reg(v, W, twg, lane);

    // out-staging (overlays own FFT region; same-wave WAR safe via in-order DS pipe):
    // slot = 512*wave + ((col + 8*wave)&511), col = 64e + lane (col encodes kx, see header)
#pragma unroll
    for (int e = 0; e < 8; ++e) {
        const int col = (e<<6) + lane;
        W[(col + (wave<<3)) & 511] = v[e];
    }
    __syncthreads();                       // REAL barrier: gather below reads ALL waves' regions

    // gather + store (R9): scratch[img][rg][col][j] => out idx = it*512 + tid
    // within this block's contiguous 32KB region. LDS read: region j, elem
    // (col + 8j)&511 -- 64 consecutive elems per wave-instruction = bank floor.
    const size_t obase = ((size_t)img << 18) + ((size_t)rg << 12);
    const int colr = tid>>3, j = tid&7;
    float2* sj = SBUF + (j<<9);
#pragma unroll
    for (int it = 0; it < 8; ++it) {
        const int col = colr + (it<<6);
        scratch[obase + (it<<9) + tid] = sj[(col + (j<<3)) & 511];
    }
}

// PSD combine for one element: F1 = Z[ky][kx], F2 = Z[-ky][-kx].
__device__ __forceinline__ void accum_psd(float2 F1, float2 F2, double& sg, double& st) {
    const float ar = 0.5f*(F1.x + F2.x), ai = 0.5f*(F1.y - F2.y);   // gen spectrum
    const float br = 0.5f*(F1.y + F2.y), bi = 0.5f*(F2.x - F1.x);   // tgt spectrum
    const float pg = fmaf(ar, ar, ai*ai) + 1e-10f;
    const float pt = fmaf(br, br, bi*bi) + 1e-10f;
    sg += (double)log10f(pg);
    st += (double)log10f(pt);
}

// Pass 2 (R7): one WAVE per conjugate column pair. Block = 256 thr = 4 waves
// = 4 independent pairs. Grid = chunk*64. NO __syncthreads anywhere.
// R9: reads use the [img][rg][col][j] layout (8x64B segments per instruction,
// 32KB apart; scratch is L3-resident).
__global__ __launch_bounds__(256, 4)
void col_fft_reduce_kernel(const float2* __restrict__ scratch,
                           const float2* __restrict__ twg,
                           double2* __restrict__ partial, int b0) {
    __shared__ float2 SBUF[4 * 512];      // 16 KB: one private 512-float2 region per wave
    const int tid = threadIdx.x, wave = tid>>6, lane = tid&63;
    const int gw = (blockIdx.x<<2) + wave;     // global wave id in dispatch
    const int img = gw>>8, t = gw&255;
    const int b = b0 + img;
    const int kxA = t;
    const int kxB = (t == 0) ? 256 : 512 - t;
    const int colA = ((kxA>>6)<<6) + ((kxA&7)<<3) + ((kxA>>3)&7);
    const int colB = ((kxB>>6)<<6) + ((kxB&7)<<3) + ((kxB>>3)&7);
    float2* W = SBUF + (wave<<9);

    // r = 64a + lane -> rg = 8a + (lane>>3), j = lane&7:
    // idx = img*2^18 + rg*4096 + col*8 + j = base + a*32768
    const size_t lanoff = ((size_t)(lane>>3)<<12) + (lane&7);
    const float2* srcA = scratch + ((size_t)img<<18) + ((size_t)colA<<3) + lanoff;
    const float2* srcB = scratch + ((size_t)img<<18) + ((size_t)colB<<3) + lanoff;
    float2 va[8], vb[8];
#pragma unroll
    for (int a = 0; a < 8; ++a) va[a] = srcA[a<<15];
#pragma unroll
    for (int a = 0; a < 8; ++a) vb[a] = srcB[a<<15];            // prefetch under FFT A

    fft512_reg(va, W, twg, lane);

    const int cc = lane>>3, dd = lane&7;
    const int kyb = cc + (dd<<3);            // ky = kyb + 64e

    // publish A natural-ky, read reversed into regs (wave-private, in-order DS)
#pragma unroll
    for (int e = 0; e < 8; ++e) W[kyb + (e<<6)] = va[e];
    lds_order();
    float2 aRev[8];
#pragma unroll
    for (int e = 0; e < 8; ++e) aRev[e] = W[(512 - (kyb + (e<<6))) & 511];
    lds_order();                             // keep FFT B's writes after these reads

    fft512_reg(vb, W, twg, lane);

#pragma unroll
    for (int e = 0; e < 8; ++e) W[kyb + (e<<6)] = vb[e];
    lds_order();
    float2 bRev[8];
#pragma unroll
    for (int e = 0; e < 8; ++e) bRev[e] = W[(512 - (kyb + (e<<6))) & 511];
    lds_order();

    // exclusion: column in box-kx  =>  skip e==0 (ky<64) and e==7 (ky>=448)
    const bool kxinA = (t < 64);             // kxA in [0,64)
    const bool kxinB = (t >= 1 && t <= 64);  // kxB = 512-t in [448,512)

    double sg = 0.0, st = 0.0;
    if (t == 0) {   // both columns self-conjugate: partner is own reversed
#pragma unroll
        for (int e = 0; e < 8; ++e) {
            if (!(kxinA && (e == 0 || e == 7))) accum_psd(va[e], aRev[e], sg, st);
            accum_psd(vb[e], bRev[e], sg, st);   // kx=256 never in box
        }
    } else {        // partner of A is B and vice versa
#pragma unroll
        for (int e = 0; e < 8; ++e) {
            if (!(kxinA && (e == 0 || e == 7))) accum_psd(va[e], bRev[e], sg, st);
            if (!(kxinB && (e == 0 || e == 7))) accum_psd(vb[e], aRev[e], sg, st);
        }
    }
#pragma unroll
    for (int off = 32; off; off >>= 1) {
        sg += __shfl_down(sg, off);
        st += __shfl_down(st, off);
    }
    if (lane == 0) partial[((size_t)b<<8) + t] = make_double2(sg, st);
}

// Sum the 256 per-pair partials of each image into accum[128]. Grid = 64 blocks.
__global__ __launch_bounds__(256)
void reduce_partial_kernel(const double2* __restrict__ partial,
                           double* __restrict__ accum) {
    __shared__ double2 red[4];
    const int img = blockIdx.x, tid = threadIdx.x, wave = tid>>6, lane = tid&63;
    const double2 p = partial[((size_t)img<<8) + tid];
    double sg = p.x, st = p.y;
#pragma unroll
    for (int off = 32; off; off >>= 1) {
        sg += __shfl_down(sg, off);
        st += __shfl_down(st, off);
    }
    if (lane == 0) red[wave] = make_double2(sg, st);
    __syncthreads();
    if (tid == 0) {
        double SG = 0.0, ST = 0.0;
#pragma unroll
        for (int w = 0; w < 4; ++w) { SG += red[w].x; ST += red[w].y; }
        accum[img] = SG;
        accum[64 + img] = ST;
    }
}

__global__ void finalize_kernel(const double* __restrict__ accum,
                                float* __restrict__ out) {
    const int lane = threadIdx.x;   // 64
    double d = fabs(accum[lane] - accum[64 + lane]) * (1.0 / 245760.0);
#pragma unroll
    for (int off = 32; off; off >>= 1) d += __shfl_down(d, off);
    if (lane == 0) out[0] = (float)(d * (1.0 / 64.0));   // WEIGHT = 1.0
}

extern "C" void kernel_launch(void* const* d_in, const int* in_sizes, int n_in,
                              void* d_out, int out_size, void* d_ws, size_t ws_size,
                              hipStream_t stream) {
    (void)in_sizes; (void)n_in; (void)out_size;
    const float* gen = (const float*)d_in[0];
    const float* tgt = (const float*)d_in[1];
    float*   out     = (float*)d_out;
    float2*  tw      = (float2*)d_ws;
    double*  accum   = (double*)((char*)d_ws + 2048);
    double2* partial = (double2*)((char*)d_ws + 4096);            // 64*256*16 B = 256 KB
    float2*  scratch = (float2*)((char*)d_ws + 266240);           // 65*4096

    const size_t per_img = (size_t)512 * 512 * sizeof(float2);
    const size_t avail = (ws_size > 266240) ? (ws_size - 266240) : 0;
    int chunk = 64;                      // shrinks to fit ws (observed: 32 -> 64 MiB, L3-resident)
    while (chunk > 1 && (size_t)chunk * per_img > avail) chunk >>= 1;

    twiddle_kernel<<<1, 256, 0, stream>>>(tw);
    for (int b0 = 0; b0 < 64; b0 += chunk) {
        row_fft_kernel<<<dim3(chunk * 64), dim3(512), 0, stream>>>(gen, tgt, tw, scratch, b0);
        col_fft_reduce_kernel<<<dim3(chunk * 64), dim3(256), 0, stream>>>(scratch, tw, partial, b0);
    }
    reduce_partial_kernel<<<dim3(64), dim3(256), 0, stream>>>(partial, accum);
    finalize_kernel<<<1, 64, 0, stream>>>(accum, out);
}